// Round 7
// baseline (377.866 us; speedup 1.0000x reference)
//
#include <hip/hip_runtime.h>

// Problem constants: B=2, S=2048, D=1024, H=16, DH=64
constexpr int BB = 2, SS = 2048, DD = 1024, HH = 16, DHH = 64;

typedef __attribute__((ext_vector_type(4))) float f32x4;
typedef __attribute__((ext_vector_type(8))) __bf16 bf16x8;      // 4 VGPRs, MFMA A/B operand
typedef __attribute__((ext_vector_type(8))) unsigned short us8; // 16B staging vector

__device__ __forceinline__ unsigned short f32_to_bf16(float f) {
    unsigned int u = __float_as_uint(f);
    u += 0x7fffu + ((u >> 16) & 1u);   // round-to-nearest-even
    return (unsigned short)(u >> 16);
}

// packed f32x2 -> bf16x2 (RNE); gfx950 has v_cvt_pk_bf16_f32
__device__ __forceinline__ ushort2 pk_bf16(float a, float b) {
#if __has_builtin(__builtin_amdgcn_cvt_pk_bf16_f32)
    typedef __attribute__((ext_vector_type(2))) __bf16 bf16x2;
    bf16x2 r = __builtin_amdgcn_cvt_pk_bf16_f32(a, b);
    return *(ushort2*)&r;
#else
    ushort2 r; r.x = f32_to_bf16(a); r.y = f32_to_bf16(b); return r;
#endif
}
__device__ __forceinline__ ushort4 pk_bf16x4(float a, float b, float c, float d) {
    const ushort2 lo = pk_bf16(a, b), hi = pk_bf16(c, d);
    ushort4 r; r.x = lo.x; r.y = lo.y; r.z = hi.x; r.w = hi.y;
    return r;
}

__device__ __forceinline__ f32x4 mfma_bf16(bf16x8 a, bf16x8 b, f32x4 c) {
    return __builtin_amdgcn_mfma_f32_16x16x32_bf16(a, b, c, 0, 0, 0);
}

// async global->LDS, 16 B per lane; LDS dest = wave-uniform base + lane*16
typedef const __attribute__((address_space(1))) unsigned int ga_u32;
typedef __attribute__((address_space(3))) unsigned int lds_u32;
__device__ __forceinline__ void gload_lds16(const unsigned short* g, unsigned short* l) {
    __builtin_amdgcn_global_load_lds((ga_u32*)g, (lds_u32*)l, 16, 0, 0);
}

// ---------------------------------------------------------------------------
// cvt_bf16: fp32 -> bf16, 8 elements/thread
// ---------------------------------------------------------------------------
__global__ __launch_bounds__(256) void cvt_bf16(const float* __restrict__ src,
                                                unsigned short* __restrict__ dst) {
    const size_t i = ((size_t)blockIdx.x * 256 + threadIdx.x) * 8;
    const float4 a = *(const float4*)(src + i);
    const float4 b = *(const float4*)(src + i + 4);
    ushort4 lo = pk_bf16x4(a.x, a.y, a.z, a.w);
    ushort4 hi = pk_bf16x4(b.x, b.y, b.z, b.w);
    us8 o;
    o[0] = lo.x; o[1] = lo.y; o[2] = lo.z; o[3] = lo.w;
    o[4] = hi.x; o[5] = hi.y; o[6] = hi.z; o[7] = hi.w;
    *(us8*)(dst + i) = o;
}

// 3-way batched variant (query/key/value in one launch)
__global__ __launch_bounds__(256) void cvt_bf16_3(const float* __restrict__ s0,
                                                  const float* __restrict__ s1,
                                                  const float* __restrict__ s2,
                                                  unsigned short* __restrict__ d0,
                                                  unsigned short* __restrict__ d1,
                                                  unsigned short* __restrict__ d2) {
    const float* src = (blockIdx.z == 0) ? s0 : (blockIdx.z == 1 ? s1 : s2);
    unsigned short* dst = (blockIdx.z == 0) ? d0 : (blockIdx.z == 1 ? d1 : d2);
    const size_t i = ((size_t)blockIdx.x * 256 + threadIdx.x) * 8;
    const float4 a = *(const float4*)(src + i);
    const float4 b = *(const float4*)(src + i + 4);
    ushort4 lo = pk_bf16x4(a.x, a.y, a.z, a.w);
    ushort4 hi = pk_bf16x4(b.x, b.y, b.z, b.w);
    us8 o;
    o[0] = lo.x; o[1] = lo.y; o[2] = lo.z; o[3] = lo.w;
    o[4] = hi.x; o[5] = hi.y; o[6] = hi.z; o[7] = hi.w;
    *(us8*)(dst + i) = o;
}

// ---------------------------------------------------------------------------
// mask_pack: int32 mask [B*S*S] -> bitmask [B*S*S/64] (bit j = chunk*64+j).
// ---------------------------------------------------------------------------
__global__ __launch_bounds__(256) void mask_pack(const int* __restrict__ mask,
                                                 unsigned long long* __restrict__ pm) {
    const int t = threadIdx.x;
    const size_t chunk = (size_t)blockIdx.x * 4 + (t >> 6);
    const int lane = t & 63;
    const int v = mask[chunk * 64 + lane];
    const unsigned long long b = __ballot(v != 0);
    if (lane == 0) pm[chunk] = b;
}

// ---------------------------------------------------------------------------
// gemm128: m97-style NT GEMM, 128x128 tile, BK=64, global_load_lds staging
// with XOR chunk swizzle (chunk c of row r stored at c^(r&7); write side is
// lane-contiguous as global_load_lds requires, read side is conflict-free).
// z-indexed args allow batching independent GEMMs in one launch.
// mode 0: write bf16 (B,H,S,DH); mode 1: bf16 (B,H,DH,S); mode 2: f32 MxN.
// MFMA 16x16x32 layouts (m89/m91): A/B idx=lane&15,k=quad*8+j;
// C/D col=lane&15 (B operand), row=quad*4+reg (A operand).
// ---------------------------------------------------------------------------
struct GemmArgs {
    const unsigned short* A;   // M x K bf16 row-major
    const unsigned short* W;   // N x K bf16 row-major
    const float* bias;
    void* out;
    float scale;
    int mode;
};

__global__ __launch_bounds__(256) void gemm128(GemmArgs g0, GemmArgs g1, GemmArgs g2) {
    constexpr int K = DD;
    __shared__ __align__(16) unsigned short Ash[128 * 64];   // 16 KB, swizzled
    __shared__ __align__(16) unsigned short Bsh[128 * 64];   // 16 KB, swizzled

    const GemmArgs ga = (blockIdx.z == 0) ? g0 : ((blockIdx.z == 1) ? g1 : g2);

    const int m0 = blockIdx.x * 128;
    const int n0 = blockIdx.y * 128;
    const int t = threadIdx.x;
    const int lane = t & 63, w = t >> 6;
    const int l15 = lane & 15, quad = lane >> 4;
    const int wm = (w >> 1) * 64, wn = (w & 1) * 64;

    // staging: slot s = base + lane; r = s>>3, stored chunk = (s&7), global
    // chunk = (s&7)^(r&7). With base % 64 == 0: r = base/8 + lane>>3 and
    // global chunk cw = (lane&7)^(lane>>3) — constant per lane.
    const int cw = (lane & 7) ^ (lane >> 3);
    const int rw = lane >> 3;

    f32x4 acc[4][4] = {};

    const unsigned short* Abase = ga.A + (size_t)m0 * K;
    const unsigned short* Wbase = ga.W + (size_t)n0 * K;

    for (int k0 = 0; k0 < K; k0 += 64) {
        __syncthreads();   // prior iteration's ds_reads done before overwrite
#pragma unroll
        for (int j = 0; j < 4; ++j) {
            const int base = j * 256 + w * 64;          // wave-uniform slot base
            const int r = (base >> 3) + rw;
            gload_lds16(Abase + (size_t)r * K + k0 + cw * 8, &Ash[base * 8]);
            gload_lds16(Wbase + (size_t)r * K + k0 + cw * 8, &Bsh[base * 8]);
        }
        __syncthreads();   // vmcnt(0) drain inserted by compiler

#pragma unroll
        for (int s = 0; s < 2; ++s) {
            const int ch = (s * 4 + quad) ^ (l15 & 7);  // de-swizzled chunk
            bf16x8 af[4], bfr[4];
#pragma unroll
            for (int mi = 0; mi < 4; ++mi)
                af[mi] = *(const bf16x8*)&Ash[(wm + mi * 16 + l15) * 64 + ch * 8];
#pragma unroll
            for (int ni = 0; ni < 4; ++ni)
                bfr[ni] = *(const bf16x8*)&Bsh[(wn + ni * 16 + l15) * 64 + ch * 8];
#pragma unroll
            for (int mi = 0; mi < 4; ++mi)
#pragma unroll
                for (int ni = 0; ni < 4; ++ni)
                    acc[mi][ni] = mfma_bf16(af[mi], bfr[ni], acc[mi][ni]);
        }
    }

#pragma unroll
    for (int ni = 0; ni < 4; ++ni) {
        const int c = n0 + wn + ni * 16 + l15;
        const float bs = ga.bias[c];
#pragma unroll
        for (int mi = 0; mi < 4; ++mi) {
#pragma unroll
            for (int r = 0; r < 4; ++r) {
                const int mrow = m0 + wm + mi * 16 + quad * 4 + r;
                const float val = (acc[mi][ni][r] + bs) * ga.scale;
                if (ga.mode == 2) {
                    ((float*)ga.out)[(size_t)mrow * DD + c] = val;
                } else {
                    const int bi2 = mrow >> 11, si = mrow & (SS - 1);
                    const int hi2 = c >> 6, di = c & (DHH - 1);
                    unsigned short* o = (unsigned short*)ga.out;
                    if (ga.mode == 0)
                        o[((size_t)(bi2 * HH + hi2) * SS + si) * DHH + di] = f32_to_bf16(val);
                    else
                        o[((size_t)(bi2 * HH + hi2) * DHH + di) * SS + si] = f32_to_bf16(val);
                }
            }
        }
    }
}

// ---------------------------------------------------------------------------
// Flash attention v3 (unchanged from R5 — verified).
// ---------------------------------------------------------------------------
__global__ __launch_bounds__(256) void flash_attn(const unsigned short* __restrict__ qws,
                                                  const unsigned short* __restrict__ kws,
                                                  const unsigned short* __restrict__ vws,
                                                  const unsigned long long* __restrict__ pm,
                                                  unsigned short* __restrict__ ctx) {
    __shared__ __align__(16) unsigned short Ksh[64][72];      // [key][d]
    __shared__ __align__(16) unsigned short Vsh[64][72];      // [d][key]
    __shared__ __align__(16) unsigned short Psh[4][16][72];   // per-wave [q][key], reused per g

    constexpr int NQT = SS / 128;
    const int qt = blockIdx.x % NQT;
    const int bh = blockIdx.x / NQT;
    const int bi = bh / HH, hi = bh % HH;

    const int t = threadIdx.x;
    const int lane = t & 63, w = t >> 6;
    const int l15 = lane & 15, quad = lane >> 4;
    const int sh4 = quad * 4;

    const unsigned short* qp = qws + (size_t)bh * SS * DHH;
    const unsigned short* kp = kws + (size_t)bh * SS * DHH;
    const unsigned short* vp = vws + (size_t)bh * DHH * SS;

    bf16x8 bq0[2], bq1[2];
    const unsigned long long* pmrow[2];
#pragma unroll
    for (int g = 0; g < 2; ++g) {
        const int q_loc = qt * 128 + g * 64 + w * 16 + l15;
        bq0[g] = *(const bf16x8*)(qp + (size_t)q_loc * DHH + quad * 8);
        bq1[g] = *(const bf16x8*)(qp + (size_t)q_loc * DHH + 32 + quad * 8);
        pmrow[g] = pm + ((size_t)bi * SS + q_loc) * (SS / 64);
    }

    f32x4 accO[2][4] = {};
    float m_run[2] = {-1e30f, -1e30f}, l_run[2] = {0.f, 0.f};
    const float NEG_INF = -__builtin_inff();

    for (int kt = 0; kt < SS / 64; ++kt) {
        __syncthreads();
#pragma unroll
        for (int hf = 0; hf < 2; ++hf) {
            const int v = t + hf * 256;
            const int row = v >> 3, off = (v & 7) * 8;
            *(us8*)&Ksh[row][off] = *(const us8*)(kp + (size_t)(kt * 64 + row) * DHH + off);
            *(us8*)&Vsh[row][off] = *(const us8*)(vp + (size_t)row * SS + kt * 64 + off);
        }
        __syncthreads();

        bf16x8 ak0[4], ak1[4], av0[4], av1[4];
#pragma unroll
        for (int i = 0; i < 4; ++i) {
            ak0[i] = *(const bf16x8*)&Ksh[i * 16 + l15][quad * 8];
            ak1[i] = *(const bf16x8*)&Ksh[i * 16 + l15][32 + quad * 8];
            av0[i] = *(const bf16x8*)&Vsh[i * 16 + l15][quad * 8];
            av1[i] = *(const bf16x8*)&Vsh[i * 16 + l15][32 + quad * 8];
        }

#pragma unroll
        for (int g = 0; g < 2; ++g) {
            const unsigned long long m64 = pmrow[g][kt];
            const unsigned int mlo = ((unsigned int)m64) >> sh4;
            const unsigned int mhi = ((unsigned int)(m64 >> 32)) >> sh4;

            float sc[4][4];
#pragma unroll
            for (int i = 0; i < 4; ++i) {
                f32x4 s4 = {};
                s4 = mfma_bf16(ak0[i], bq0[g], s4);
                s4 = mfma_bf16(ak1[i], bq1[g], s4);
                const unsigned int mw = (i & 2) ? mhi : mlo;
#pragma unroll
                for (int r = 0; r < 4; ++r)
                    sc[i][r] = ((mw >> ((i & 1) * 16 + r)) & 1u) ? NEG_INF : s4[r];
            }

            float tm = sc[0][0];
#pragma unroll
            for (int i = 0; i < 4; ++i)
#pragma unroll
                for (int r = 0; r < 4; ++r) tm = fmaxf(tm, sc[i][r]);
            tm = fmaxf(tm, __shfl_xor(tm, 16));
            tm = fmaxf(tm, __shfl_xor(tm, 32));
            const float mn = fmaxf(m_run[g], tm);
            const float alpha = __builtin_amdgcn_exp2f(m_run[g] - mn);
            float rs = 0.f;
#pragma unroll
            for (int i = 0; i < 4; ++i)
#pragma unroll
                for (int r = 0; r < 4; ++r) {
                    const float p = __builtin_amdgcn_exp2f(sc[i][r] - mn);
                    sc[i][r] = p;
                    rs += p;
                }
            rs += __shfl_xor(rs, 16);
            rs += __shfl_xor(rs, 32);
            l_run[g] = l_run[g] * alpha + rs;
            m_run[g] = mn;
#pragma unroll
            for (int i = 0; i < 4; ++i)
#pragma unroll
                for (int r = 0; r < 4; ++r) accO[g][i][r] *= alpha;

#pragma unroll
            for (int i = 0; i < 4; ++i)
                *(ushort4*)&Psh[w][l15][i * 16 + sh4] =
                    pk_bf16x4(sc[i][0], sc[i][1], sc[i][2], sc[i][3]);
            __asm__ volatile("s_waitcnt lgkmcnt(0)" ::: "memory");

            const bf16x8 p0 = *(const bf16x8*)&Psh[w][l15][quad * 8];
            const bf16x8 p1 = *(const bf16x8*)&Psh[w][l15][32 + quad * 8];
#pragma unroll
            for (int i = 0; i < 4; ++i) {
                accO[g][i] = mfma_bf16(av0[i], p0, accO[g][i]);
                accO[g][i] = mfma_bf16(av1[i], p1, accO[g][i]);
            }
        }
    }

#pragma unroll
    for (int g = 0; g < 2; ++g) {
        const float inv = 1.0f / l_run[g];
        unsigned short* cb = ctx + ((size_t)(bi * SS) + qt * 128 + g * 64 + w * 16 + l15) * DD
                                 + hi * DHH;
#pragma unroll
        for (int i = 0; i < 4; ++i)
            *(ushort4*)&cb[i * 16 + sh4] = pk_bf16x4(accO[g][i][0] * inv, accO[g][i][1] * inv,
                                                     accO[g][i][2] * inv, accO[g][i][3] * inv);
    }
}

// ---------------------------------------------------------------------------
// score_h0 (unchanged from R5 — verified).
// ---------------------------------------------------------------------------
__global__ __launch_bounds__(256) void score_h0(const unsigned short* __restrict__ q0,
                                                const unsigned short* __restrict__ k0,
                                                const unsigned long long* __restrict__ pm,
                                                float* __restrict__ outp,
                                                float2* __restrict__ stats) {
    __shared__ __align__(16) unsigned short Ksh[64][72];

    const int kc = blockIdx.x & 3;
    const int qt = (blockIdx.x >> 2) & 31;
    const int bi = blockIdx.x >> 7;

    const int t = threadIdx.x;
    const int lane = t & 63, w = t >> 6;
    const int l15 = lane & 15, quad = lane >> 4;
    const int sh4 = quad * 4;

    const int q = qt * 64 + w * 16 + l15;
    const unsigned short* qp = q0 + ((size_t)bi * SS + q) * DHH;
    const bf16x8 bq0 = *(const bf16x8*)(qp + quad * 8);
    const bf16x8 bq1 = *(const bf16x8*)(qp + 32 + quad * 8);

    const unsigned short* kp = k0 + (size_t)bi * SS * DHH;
    const unsigned long long* pmq = pm + ((size_t)bi * SS + q) * (SS / 64);
    float* orow = outp + ((size_t)bi * SS + q) * SS;

    float m_l = -1e30f, l_l = 0.f;

    for (int kt = 0; kt < 8; ++kt) {
        const int key0 = kc * 512 + kt * 64;
        __syncthreads();
#pragma unroll
        for (int hf = 0; hf < 2; ++hf) {
            const int v = t + hf * 256;
            const int row = v >> 3, off = (v & 7) * 8;
            *(us8*)&Ksh[row][off] = *(const us8*)(kp + (size_t)(key0 + row) * DHH + off);
        }
        __syncthreads();

        const unsigned long long m64 = pmq[kc * 8 + kt];
        const unsigned int mlo = ((unsigned int)m64) >> sh4;
        const unsigned int mhi = ((unsigned int)(m64 >> 32)) >> sh4;

        float sc[4][4];
        float lm = -1e30f;
#pragma unroll
        for (int i = 0; i < 4; ++i) {
            const bf16x8 ak0 = *(const bf16x8*)&Ksh[i * 16 + l15][quad * 8];
            const bf16x8 ak1 = *(const bf16x8*)&Ksh[i * 16 + l15][32 + quad * 8];
            f32x4 s4 = {};
            s4 = mfma_bf16(ak0, bq0, s4);
            s4 = mfma_bf16(ak1, bq1, s4);
            const unsigned int mw = (i & 2) ? mhi : mlo;
            float4 ov;
#pragma unroll
            for (int r = 0; r < 4; ++r) {
                const float s = ((mw >> ((i & 1) * 16 + r)) & 1u) ? -1e18f : s4[r];
                sc[i][r] = s;
                lm = fmaxf(lm, s);
            }
            ov.x = sc[i][0]; ov.y = sc[i][1]; ov.z = sc[i][2]; ov.w = sc[i][3];
            *(float4*)&orow[key0 + i * 16 + sh4] = ov;
        }

        const float mn = fmaxf(m_l, lm);
        float rs = 0.f;
#pragma unroll
        for (int i = 0; i < 4; ++i)
#pragma unroll
            for (int r = 0; r < 4; ++r) rs += __builtin_amdgcn_exp2f(sc[i][r] - mn);
        l_l = l_l * __builtin_amdgcn_exp2f(m_l - mn) + rs;
        m_l = mn;
    }

#pragma unroll
    for (int d = 16; d <= 32; d <<= 1) {
        const float mo = __shfl_xor(m_l, d);
        const float lo = __shfl_xor(l_l, d);
        const float mn = fmaxf(m_l, mo);
        l_l = l_l * __builtin_amdgcn_exp2f(m_l - mn) + lo * __builtin_amdgcn_exp2f(mo - mn);
        m_l = mn;
    }
    if (quad == 0) {
        float2 st; st.x = m_l; st.y = l_l;
        stats[((size_t)(bi * 4 + kc)) * SS + q] = st;
    }
}

// ---------------------------------------------------------------------------
// scale_h0 (unchanged from R5 — verified).
// ---------------------------------------------------------------------------
__global__ __launch_bounds__(256) void scale_h0(float* __restrict__ scores,
                                                const float2* __restrict__ stats) {
    const int bi = blockIdx.x >> 11;
    const int si = blockIdx.x & (SS - 1);
    const int t = threadIdx.x;

    float M = -1e30f, L = 0.f;
#pragma unroll
    for (int c = 0; c < 4; ++c) {
        const float2 st = stats[((size_t)(bi * 4 + c)) * SS + si];
        const float mn = fmaxf(M, st.x);
        L = L * __builtin_amdgcn_exp2f(M - mn) + st.y * __builtin_amdgcn_exp2f(st.x - mn);
        M = mn;
    }
    const float inv = 1.0f / L;

    float* row = scores + (size_t)blockIdx.x * SS;
    const int base = t * 8;
    float4 a = *(const float4*)&row[base];
    float4 b = *(const float4*)&row[base + 4];
    a.x = __builtin_amdgcn_exp2f(a.x - M) * inv;
    a.y = __builtin_amdgcn_exp2f(a.y - M) * inv;
    a.z = __builtin_amdgcn_exp2f(a.z - M) * inv;
    a.w = __builtin_amdgcn_exp2f(a.w - M) * inv;
    b.x = __builtin_amdgcn_exp2f(b.x - M) * inv;
    b.y = __builtin_amdgcn_exp2f(b.y - M) * inv;
    b.z = __builtin_amdgcn_exp2f(b.z - M) * inv;
    b.w = __builtin_amdgcn_exp2f(b.w - M) * inv;
    *(float4*)&row[base] = a;
    *(float4*)&row[base + 4] = b;
}

// ---------------------------------------------------------------------------
// d_out: output (B*S*D f32, 16 MB) ++ top_attn (B*S*S f32, 32 MB)
// d_ws: q0/k0 (1 MB) + pm (1 MB) + stats (128 KB) [+ Xv (8 MB) if it fits]
// If d_ws can't hold Xv, it lives in the kws region and the k-GEMM is
// launched after the v-GEMM consumed it (both paths deterministic).
// ---------------------------------------------------------------------------
extern "C" void kernel_launch(void* const* d_in, const int* in_sizes, int n_in,
                              void* d_out, int out_size, void* d_ws, size_t ws_size,
                              hipStream_t stream) {
    const float* key_   = (const float*)d_in[0];
    const float* value_ = (const float*)d_in[1];
    const float* query_ = (const float*)d_in[2];
    const int*   mask_  = (const int*)d_in[3];
    const float* Wk = (const float*)d_in[4];
    const float* bk = (const float*)d_in[5];
    const float* Wv = (const float*)d_in[6];
    const float* bv = (const float*)d_in[7];
    const float* Wq = (const float*)d_in[8];
    const float* bq = (const float*)d_in[9];
    const float* Wo = (const float*)d_in[10];
    const float* bo = (const float*)d_in[11];

    constexpr size_t XS  = (size_t)BB * SS * DD;  // 4194304 elements
    constexpr size_t WSZ = (size_t)DD * DD;       // 1048576 elements

    float* out_f = (float*)d_out;
    unsigned short* scratch = (unsigned short*)(out_f + XS);
    unsigned short* qws = scratch;            // (B,H,S,DH)
    unsigned short* kws = qws + XS;           // (B,H,S,DH)
    unsigned short* vws = kws + XS;           // (B,H,DH,S)
    unsigned short* ctx = vws + XS;           // (B,S,D) — holds Wq/Wk/Wv bf16 pre-flash

    unsigned short* q0 = (unsigned short*)d_ws;
    unsigned short* k0 = q0 + (size_t)BB * SS * DHH;
    unsigned long long* pm = (unsigned long long*)(k0 + (size_t)BB * SS * DHH);
    float2* stats = (float2*)(pm + (size_t)BB * SS * (SS / 64));
    constexpr size_t WS_CORE = ((size_t)BB * SS * DHH * 2) * 2        // q0+k0
                             + (size_t)BB * SS * (SS / 64) * 8        // pm
                             + (size_t)BB * 4 * SS * 8;               // stats

    const bool fused = ws_size >= WS_CORE + XS * 2;   // room for Xv in d_ws?

    unsigned short* Xq  = (unsigned short*)out_f;           // 8 MB (dead till out-GEMM)
    unsigned short* Xk  = Xq + XS;                          // 8 MB
    unsigned short* Xv  = fused ? (unsigned short*)((char*)d_ws + WS_CORE) : kws;
    unsigned short* Wqb = ctx;                              // ctx free till flash
    unsigned short* Wkb = Wqb + WSZ;
    unsigned short* Wvb = Wkb + WSZ;
    unsigned short* Wob = qws;                              // qws free after flash

    mask_pack<<<BB * SS * (SS / 64) / 4, 256, 0, stream>>>(mask_, pm);

    cvt_bf16_3<<<dim3(XS / 2048, 1, 3), 256, 0, stream>>>(query_, key_, value_, Xq, Xk, Xv);
    cvt_bf16<<<WSZ / 2048, 256, 0, stream>>>(Wq, Wqb);
    cvt_bf16<<<WSZ / 2048, 256, 0, stream>>>(Wk, Wkb);
    cvt_bf16<<<WSZ / 2048, 256, 0, stream>>>(Wv, Wvb);

    const float qscale = 0.125f * 1.4426950408889634f;   // 1/sqrt(DH) * log2(e)

    GemmArgs gq = {Xq, Wqb, bq, qws, qscale, 0};
    GemmArgs gk = {Xk, Wkb, bk, kws, 1.0f,   0};
    GemmArgs gv = {Xv, Wvb, bv, vws, 1.0f,   1};

    if (fused) {
        gemm128<<<dim3(32, 8, 3), 256, 0, stream>>>(gq, gk, gv);
    } else {
        // v reads Xv in kws region -> k (which writes kws) must run after
        gemm128<<<dim3(32, 8, 2), 256, 0, stream>>>(gq, gv, gv);
        gemm128<<<dim3(32, 8, 1), 256, 0, stream>>>(gk, gk, gk);
    }

    // save head-0 q/k before the scratch region is clobbered at the end
    for (int b = 0; b < BB; ++b) {
        hipMemcpyAsync(q0 + (size_t)b * SS * DHH, qws + (size_t)(b * HH) * SS * DHH,
                       (size_t)SS * DHH * sizeof(unsigned short),
                       hipMemcpyDeviceToDevice, stream);
        hipMemcpyAsync(k0 + (size_t)b * SS * DHH, kws + (size_t)(b * HH) * SS * DHH,
                       (size_t)SS * DHH * sizeof(unsigned short),
                       hipMemcpyDeviceToDevice, stream);
    }

    flash_attn<<<BB * HH * (SS / 128), 256, 0, stream>>>(qws, kws, vws, pm, ctx);

    cvt_bf16<<<WSZ / 2048, 256, 0, stream>>>(Wo, Wob);
    GemmArgs go = {ctx, Wob, bo, out_f, 1.0f, 2};
    gemm128<<<dim3(32, 8, 1), 256, 0, stream>>>(go, go, go);

    score_h0<<<BB * 32 * 4, 256, 0, stream>>>(q0, k0, pm, out_f + XS, stats);
    scale_h0<<<BB * SS, 256, 0, stream>>>(out_f + XS, stats);
}